// Round 1
// baseline (190.563 us; speedup 1.0000x reference)
//
#include <hip/hip_runtime.h>
#include <math.h>

#define H 256
#define TILE 256

// Kernel 1: v[c][h] = sum_l w_c(l) * table[loc[l]][h], c = 0..3
// weights: w0=beta*alpha, w1=beta*(1-alpha), w2=(1-beta)*alpha, w3=(1-beta)*(1-alpha)
// alpha = tu/(tu+tl), beta = lu/(lu+ll) after clipping.
__global__ __launch_bounds__(256) void strnn_gather(
    const float* __restrict__ td_u, const float* __restrict__ td_l,
    const float* __restrict__ ld_u, const float* __restrict__ ld_l,
    const int* __restrict__ loc, const float* __restrict__ table,
    float* __restrict__ v, int L)
{
    __shared__ int   s_loc[TILE];
    __shared__ float s_w0[TILE], s_w1[TILE], s_w2[TILE], s_w3[TILE];
    const int t = threadIdx.x;

    float a0 = 0.f, a1 = 0.f, a2 = 0.f, a3 = 0.f;

    for (int base = blockIdx.x * TILE; base < L; base += gridDim.x * TILE) {
        const int l = base + t;
        const bool ok = (l < L);
        float tu = ok ? fminf(fmaxf(td_u[l], 0.f), 1440.f) : 1.f;
        float tl = ok ? fminf(fmaxf(td_l[l], 0.f), 1440.f) : 1.f;
        float lu = ok ? fminf(fmaxf(ld_u[l], 0.f), 40.f)   : 1.f;
        float ll = ok ? fminf(fmaxf(ld_l[l], 0.f), 40.f)   : 1.f;
        float al = tu / (tu + tl);
        float be = lu / (lu + ll);
        float w0 = be * al, w1 = be * (1.f - al);
        float w2 = (1.f - be) * al, w3 = (1.f - be) * (1.f - al);
        if (!ok) { w0 = w1 = w2 = w3 = 0.f; }
        s_w0[t] = w0; s_w1[t] = w1; s_w2[t] = w2; s_w3[t] = w3;
        s_loc[t] = ok ? loc[l] : 0;
        __syncthreads();

        // each thread owns column h = t; 8 independent row loads in flight
        for (int j = 0; j < TILE; j += 8) {
            float e[8];
            #pragma unroll
            for (int u = 0; u < 8; ++u)
                e[u] = table[(size_t)s_loc[j + u] * H + t];
            #pragma unroll
            for (int u = 0; u < 8; ++u) {
                a0 = fmaf(s_w0[j + u], e[u], a0);
                a1 = fmaf(s_w1[j + u], e[u], a1);
                a2 = fmaf(s_w2[j + u], e[u], a2);
                a3 = fmaf(s_w3[j + u], e[u], a3);
            }
        }
        __syncthreads();
    }

    atomicAdd(&v[0 * H + t], a0);
    atomicAdd(&v[1 * H + t], a1);
    atomicAdd(&v[2 * H + t], a2);
    atomicAdd(&v[3 * H + t], a3);
}

// Kernel 2a: one wave per output row h (256 waves total):
//   p[h] = sum_k Wtu[h,k]*v1[k] + Wtl[h,k]*v2[k]
//   q[h] = sum_k Wtu[h,k]*v3[k] + Wtl[h,k]*v4[k]
//   u[h] = sum_k Wih[h,k]*hx[k]
__global__ __launch_bounds__(256) void strnn_mid(
    const float* __restrict__ Wtu, const float* __restrict__ Wtl,
    const float* __restrict__ Wih, const float* __restrict__ hx,
    const float* __restrict__ v, float* __restrict__ pqu)
{
    const int wave = (blockIdx.x * blockDim.x + threadIdx.x) >> 6;  // = h
    const int lane = threadIdx.x & 63;
    const float* v1 = v;
    const float* v2 = v + H;
    const float* v3 = v + 2 * H;
    const float* v4 = v + 3 * H;

    float p = 0.f, q = 0.f, u = 0.f;
    #pragma unroll
    for (int i = 0; i < H; i += 64) {
        const int k = i + lane;
        const float wtu = Wtu[wave * H + k];
        const float wtl = Wtl[wave * H + k];
        p = fmaf(wtu, v1[k], fmaf(wtl, v2[k], p));
        q = fmaf(wtu, v3[k], fmaf(wtl, v4[k], q));
        u = fmaf(Wih[wave * H + k], hx[k], u);
    }
    #pragma unroll
    for (int off = 32; off > 0; off >>= 1) {
        p += __shfl_down(p, off, 64);
        q += __shfl_down(q, off, 64);
        u += __shfl_down(u, off, 64);
    }
    if (lane == 0) {
        pqu[wave]         = p;
        pqu[H + wave]     = q;
        pqu[2 * H + wave] = u;
    }
}

// Kernel 2b: out[h] = sigmoid( sum_k Wsu[h,k]*p[k] + Wsl[h,k]*q[k] + u[h] )
__global__ __launch_bounds__(256) void strnn_out(
    const float* __restrict__ Wsu, const float* __restrict__ Wsl,
    const float* __restrict__ pqu, float* __restrict__ out)
{
    const int wave = (blockIdx.x * blockDim.x + threadIdx.x) >> 6;  // = h
    const int lane = threadIdx.x & 63;
    const float* p = pqu;
    const float* q = pqu + H;
    const float* u = pqu + 2 * H;

    float s = 0.f;
    #pragma unroll
    for (int i = 0; i < H; i += 64) {
        const int k = i + lane;
        s = fmaf(Wsu[wave * H + k], p[k], fmaf(Wsl[wave * H + k], q[k], s));
    }
    #pragma unroll
    for (int off = 32; off > 0; off >>= 1)
        s += __shfl_down(s, off, 64);
    if (lane == 0)
        out[wave] = 1.f / (1.f + expf(-(s + u[wave])));
}

extern "C" void kernel_launch(void* const* d_in, const int* in_sizes, int n_in,
                              void* d_out, int out_size, void* d_ws, size_t ws_size,
                              hipStream_t stream) {
    const float* td_u  = (const float*)d_in[0];
    const float* td_l  = (const float*)d_in[1];
    const float* ld_u  = (const float*)d_in[2];
    const float* ld_l  = (const float*)d_in[3];
    const int*   loc   = (const int*)d_in[4];
    const float* hx    = (const float*)d_in[5];
    const float* Wih   = (const float*)d_in[6];
    const float* Wtu   = (const float*)d_in[7];
    const float* Wtl   = (const float*)d_in[8];
    const float* Wsu   = (const float*)d_in[9];
    const float* Wsl   = (const float*)d_in[10];
    const float* table = (const float*)d_in[11];
    const int L = in_sizes[0];

    float* v   = (float*)d_ws;   // 4*H accumulators
    float* pqu = v + 4 * H;      // p, q, usr (3*H)

    // ws is re-poisoned to 0xAA before every launch — zero the accumulators.
    hipMemsetAsync(v, 0, 4 * H * sizeof(float), stream);

    strnn_gather<<<512, 256, 0, stream>>>(td_u, td_l, ld_u, ld_l, loc, table, v, L);
    strnn_mid<<<64, 256, 0, stream>>>(Wtu, Wtl, Wih, hx, v, pqu);
    strnn_out<<<64, 256, 0, stream>>>(Wsu, Wsl, pqu, (float*)d_out);
}

// Round 2
// 186.248 us; speedup vs baseline: 1.0232x; 1.0232x over previous
//
#include <hip/hip_runtime.h>
#include <math.h>

#define H 256
#define TILE 256

// Kernel 1: v[c][h] = sum_l w_c(l) * table[loc[l]][h], c = 0..3
// w0=beta*alpha, w1=beta*(1-alpha), w2=(1-beta)*alpha, w3=(1-beta)*(1-alpha)
// alpha = tu/(tu+tl), beta = lu/(lu+ll) after clipping.
//
// Layout: each block stages 256 rows' {weights(float4), loc} in LDS.
// Wave w owns rows [64w, 64w+64): one global_load_dwordx4 per lane reads the
// FULL 1 KB table row per wave instruction (lane k -> cols 4k..4k+3).
// Per row: 1 ds_read_b128 (broadcast float4 weights) + 1 ds_read_b32 (loc)
// + 16 FMAs. Cross-wave reduction in LDS, then 4 atomicAdds per thread
// (512 adds/address total).
__global__ __launch_bounds__(256) void strnn_gather(
    const float* __restrict__ td_u, const float* __restrict__ td_l,
    const float* __restrict__ ld_u, const float* __restrict__ ld_l,
    const int* __restrict__ loc, const float* __restrict__ table,
    float* __restrict__ v, int L)
{
    __shared__ float4 s_w[TILE];       //  4 KB
    __shared__ int    s_loc[TILE];     //  1 KB
    __shared__ float  s_red[4][4][H];  // 16 KB: [wave][c][col]
    const int t    = threadIdx.x;
    const int wave = t >> 6;
    const int lane = t & 63;

    float4 a0 = {0,0,0,0}, a1 = {0,0,0,0}, a2 = {0,0,0,0}, a3 = {0,0,0,0};

    for (int base = blockIdx.x * TILE; base < L; base += gridDim.x * TILE) {
        const int l = base + t;
        const bool ok = (l < L);
        float tu = ok ? fminf(fmaxf(td_u[l], 0.f), 1440.f) : 1.f;
        float tl = ok ? fminf(fmaxf(td_l[l], 0.f), 1440.f) : 1.f;
        float lu = ok ? fminf(fmaxf(ld_u[l], 0.f), 40.f)   : 1.f;
        float ll = ok ? fminf(fmaxf(ld_l[l], 0.f), 40.f)   : 1.f;
        float al = tu / (tu + tl);
        float be = lu / (lu + ll);
        float w0 = be * al, w1 = be * (1.f - al);
        float w2 = (1.f - be) * al, w3 = (1.f - be) * (1.f - al);
        if (!ok) { w0 = w1 = w2 = w3 = 0.f; }
        s_w[t]   = make_float4(w0, w1, w2, w3);
        s_loc[t] = ok ? loc[l] : 0;
        __syncthreads();

        const int r0 = wave * 64;
        #pragma unroll 4
        for (int j = 0; j < 64; j += 4) {
            float4 w[4], e[4];
            #pragma unroll
            for (int u = 0; u < 4; ++u)
                w[u] = s_w[r0 + j + u];
            #pragma unroll
            for (int u = 0; u < 4; ++u)
                e[u] = *(const float4*)(table + (size_t)s_loc[r0 + j + u] * H + 4 * lane);
            #pragma unroll
            for (int u = 0; u < 4; ++u) {
                a0.x = fmaf(w[u].x, e[u].x, a0.x);
                a0.y = fmaf(w[u].x, e[u].y, a0.y);
                a0.z = fmaf(w[u].x, e[u].z, a0.z);
                a0.w = fmaf(w[u].x, e[u].w, a0.w);
                a1.x = fmaf(w[u].y, e[u].x, a1.x);
                a1.y = fmaf(w[u].y, e[u].y, a1.y);
                a1.z = fmaf(w[u].y, e[u].z, a1.z);
                a1.w = fmaf(w[u].y, e[u].w, a1.w);
                a2.x = fmaf(w[u].z, e[u].x, a2.x);
                a2.y = fmaf(w[u].z, e[u].y, a2.y);
                a2.z = fmaf(w[u].z, e[u].z, a2.z);
                a2.w = fmaf(w[u].z, e[u].w, a2.w);
                a3.x = fmaf(w[u].w, e[u].x, a3.x);
                a3.y = fmaf(w[u].w, e[u].y, a3.y);
                a3.z = fmaf(w[u].w, e[u].z, a3.z);
                a3.w = fmaf(w[u].w, e[u].w, a3.w);
            }
        }
        __syncthreads();
    }

    // cross-wave block reduction in LDS
    *(float4*)&s_red[wave][0][4 * lane] = a0;
    *(float4*)&s_red[wave][1][4 * lane] = a1;
    *(float4*)&s_red[wave][2][4 * lane] = a2;
    *(float4*)&s_red[wave][3][4 * lane] = a3;
    __syncthreads();
    #pragma unroll
    for (int c = 0; c < 4; ++c) {
        float s = s_red[0][c][t] + s_red[1][c][t] + s_red[2][c][t] + s_red[3][c][t];
        atomicAdd(&v[c * H + t], s);
    }
}

// Kernel 2a: one wave per output row h:
//   p[h] = Wtu[h,:]·v1 + Wtl[h,:]·v2
//   q[h] = Wtu[h,:]·v3 + Wtl[h,:]·v4
//   u[h] = Wih[h,:]·hx
__global__ __launch_bounds__(256) void strnn_mid(
    const float* __restrict__ Wtu, const float* __restrict__ Wtl,
    const float* __restrict__ Wih, const float* __restrict__ hx,
    const float* __restrict__ v, float* __restrict__ pqu)
{
    const int wave = (blockIdx.x * blockDim.x + threadIdx.x) >> 6;  // = h
    const int lane = threadIdx.x & 63;
    const float* v1 = v;
    const float* v2 = v + H;
    const float* v3 = v + 2 * H;
    const float* v4 = v + 3 * H;

    float p = 0.f, q = 0.f, u = 0.f;
    #pragma unroll
    for (int i = 0; i < H; i += 64) {
        const int k = i + lane;
        const float wtu = Wtu[wave * H + k];
        const float wtl = Wtl[wave * H + k];
        p = fmaf(wtu, v1[k], fmaf(wtl, v2[k], p));
        q = fmaf(wtu, v3[k], fmaf(wtl, v4[k], q));
        u = fmaf(Wih[wave * H + k], hx[k], u);
    }
    #pragma unroll
    for (int off = 32; off > 0; off >>= 1) {
        p += __shfl_down(p, off, 64);
        q += __shfl_down(q, off, 64);
        u += __shfl_down(u, off, 64);
    }
    if (lane == 0) {
        pqu[wave]         = p;
        pqu[H + wave]     = q;
        pqu[2 * H + wave] = u;
    }
}

// Kernel 2b: out[h] = sigmoid( Wsu[h,:]·p + Wsl[h,:]·q + u[h] )
__global__ __launch_bounds__(256) void strnn_out(
    const float* __restrict__ Wsu, const float* __restrict__ Wsl,
    const float* __restrict__ pqu, float* __restrict__ out)
{
    const int wave = (blockIdx.x * blockDim.x + threadIdx.x) >> 6;  // = h
    const int lane = threadIdx.x & 63;
    const float* p = pqu;
    const float* q = pqu + H;
    const float* u = pqu + 2 * H;

    float s = 0.f;
    #pragma unroll
    for (int i = 0; i < H; i += 64) {
        const int k = i + lane;
        s = fmaf(Wsu[wave * H + k], p[k], fmaf(Wsl[wave * H + k], q[k], s));
    }
    #pragma unroll
    for (int off = 32; off > 0; off >>= 1)
        s += __shfl_down(s, off, 64);
    if (lane == 0)
        out[wave] = 1.f / (1.f + expf(-(s + u[wave])));
}

extern "C" void kernel_launch(void* const* d_in, const int* in_sizes, int n_in,
                              void* d_out, int out_size, void* d_ws, size_t ws_size,
                              hipStream_t stream) {
    const float* td_u  = (const float*)d_in[0];
    const float* td_l  = (const float*)d_in[1];
    const float* ld_u  = (const float*)d_in[2];
    const float* ld_l  = (const float*)d_in[3];
    const int*   loc   = (const int*)d_in[4];
    const float* hx    = (const float*)d_in[5];
    const float* Wih   = (const float*)d_in[6];
    const float* Wtu   = (const float*)d_in[7];
    const float* Wtl   = (const float*)d_in[8];
    const float* Wsu   = (const float*)d_in[9];
    const float* Wsl   = (const float*)d_in[10];
    const float* table = (const float*)d_in[11];
    const int L = in_sizes[0];

    float* v   = (float*)d_ws;   // 4*H accumulators
    float* pqu = v + 4 * H;      // p, q, usr (3*H)

    // ws is re-poisoned to 0xAA before every launch — zero the accumulators.
    hipMemsetAsync(v, 0, 4 * H * sizeof(float), stream);

    strnn_gather<<<512, 256, 0, stream>>>(td_u, td_l, ld_u, ld_l, loc, table, v, L);
    strnn_mid<<<64, 256, 0, stream>>>(Wtu, Wtl, Wih, hx, v, pqu);
    strnn_out<<<64, 256, 0, stream>>>(Wsu, Wsl, pqu, (float*)d_out);
}

// Round 3
// 183.362 us; speedup vs baseline: 1.0393x; 1.0157x over previous
//
#include <hip/hip_runtime.h>
#include <math.h>

#define H 256
#define TILE 256

// Kernel 1: v[c][h] = sum_l w_c(l) * table[loc[l]][h], c = 0..3
// w0=beta*alpha, w1=beta*(1-alpha), w2=(1-beta)*alpha, w3=(1-beta)*(1-alpha)
// alpha = tu/(tu+tl), beta = lu/(lu+ll) after clipping.
//
// Row-per-wave: wave w owns 64 rows of the block's 256-row tile; one
// global_load_dwordx4 per lane covers a full 1 KB table row per wave
// instruction. 8 rows' loads in flight per wave (8 KB/wave, 64 KB/CU at
// 8 waves/CU) to ride out ~900-cycle HBM latency. Weights broadcast from
// LDS as float4 (1 ds_read_b128/row). Cross-wave LDS reduction, then 4
// atomicAdds per thread (512 adds/address total).
__global__ __launch_bounds__(256) void strnn_gather(
    const float* __restrict__ td_u, const float* __restrict__ td_l,
    const float* __restrict__ ld_u, const float* __restrict__ ld_l,
    const int* __restrict__ loc, const float* __restrict__ table,
    float* __restrict__ v, int L)
{
    __shared__ float4 s_w[TILE];       //  4 KB
    __shared__ int    s_loc[TILE];     //  1 KB
    __shared__ float  s_red[4][4][H];  // 16 KB: [wave][c][col]
    const int t    = threadIdx.x;
    const int wave = t >> 6;
    const int lane = t & 63;

    float4 a0 = {0,0,0,0}, a1 = {0,0,0,0}, a2 = {0,0,0,0}, a3 = {0,0,0,0};

    for (int base = blockIdx.x * TILE; base < L; base += gridDim.x * TILE) {
        const int l = base + t;
        const bool ok = (l < L);
        float tu = ok ? fminf(fmaxf(td_u[l], 0.f), 1440.f) : 1.f;
        float tl = ok ? fminf(fmaxf(td_l[l], 0.f), 1440.f) : 1.f;
        float lu = ok ? fminf(fmaxf(ld_u[l], 0.f), 40.f)   : 1.f;
        float ll = ok ? fminf(fmaxf(ld_l[l], 0.f), 40.f)   : 1.f;
        float al = tu / (tu + tl);
        float be = lu / (lu + ll);
        float w0 = be * al, w1 = be * (1.f - al);
        float w2 = (1.f - be) * al, w3 = (1.f - be) * (1.f - al);
        if (!ok) { w0 = w1 = w2 = w3 = 0.f; }
        s_w[t]   = make_float4(w0, w1, w2, w3);
        s_loc[t] = ok ? loc[l] : 0;
        __syncthreads();

        const int r0 = wave * 64;
        #pragma unroll 2
        for (int j = 0; j < 64; j += 8) {
            const float4* addr[8];
            #pragma unroll
            for (int u = 0; u < 8; ++u)
                addr[u] = (const float4*)(table + (size_t)s_loc[r0 + j + u] * H + 4 * lane);
            float4 w[8], e[8];
            #pragma unroll
            for (int u = 0; u < 8; ++u)
                e[u] = *addr[u];                 // 8 loads in flight
            #pragma unroll
            for (int u = 0; u < 8; ++u)
                w[u] = s_w[r0 + j + u];          // broadcast ds_read_b128
            #pragma unroll
            for (int u = 0; u < 8; ++u) {
                a0.x = fmaf(w[u].x, e[u].x, a0.x);
                a0.y = fmaf(w[u].x, e[u].y, a0.y);
                a0.z = fmaf(w[u].x, e[u].z, a0.z);
                a0.w = fmaf(w[u].x, e[u].w, a0.w);
                a1.x = fmaf(w[u].y, e[u].x, a1.x);
                a1.y = fmaf(w[u].y, e[u].y, a1.y);
                a1.z = fmaf(w[u].y, e[u].z, a1.z);
                a1.w = fmaf(w[u].y, e[u].w, a1.w);
                a2.x = fmaf(w[u].z, e[u].x, a2.x);
                a2.y = fmaf(w[u].z, e[u].y, a2.y);
                a2.z = fmaf(w[u].z, e[u].z, a2.z);
                a2.w = fmaf(w[u].z, e[u].w, a2.w);
                a3.x = fmaf(w[u].w, e[u].x, a3.x);
                a3.y = fmaf(w[u].w, e[u].y, a3.y);
                a3.z = fmaf(w[u].w, e[u].z, a3.z);
                a3.w = fmaf(w[u].w, e[u].w, a3.w);
            }
        }
        __syncthreads();
    }

    // cross-wave block reduction in LDS
    *(float4*)&s_red[wave][0][4 * lane] = a0;
    *(float4*)&s_red[wave][1][4 * lane] = a1;
    *(float4*)&s_red[wave][2][4 * lane] = a2;
    *(float4*)&s_red[wave][3][4 * lane] = a3;
    __syncthreads();
    #pragma unroll
    for (int c = 0; c < 4; ++c) {
        float s = s_red[0][c][t] + s_red[1][c][t] + s_red[2][c][t] + s_red[3][c][t];
        atomicAdd(&v[c * H + t], s);
    }
}

// Kernel 2a: one wave per output row h:
//   p[h] = Wtu[h,:]·v1 + Wtl[h,:]·v2
//   q[h] = Wtu[h,:]·v3 + Wtl[h,:]·v4
//   u[h] = Wih[h,:]·hx
__global__ __launch_bounds__(256) void strnn_mid(
    const float* __restrict__ Wtu, const float* __restrict__ Wtl,
    const float* __restrict__ Wih, const float* __restrict__ hx,
    const float* __restrict__ v, float* __restrict__ pqu)
{
    const int wave = (blockIdx.x * blockDim.x + threadIdx.x) >> 6;  // = h
    const int lane = threadIdx.x & 63;
    const float* v1 = v;
    const float* v2 = v + H;
    const float* v3 = v + 2 * H;
    const float* v4 = v + 3 * H;

    float p = 0.f, q = 0.f, u = 0.f;
    #pragma unroll
    for (int i = 0; i < H; i += 64) {
        const int k = i + lane;
        const float wtu = Wtu[wave * H + k];
        const float wtl = Wtl[wave * H + k];
        p = fmaf(wtu, v1[k], fmaf(wtl, v2[k], p));
        q = fmaf(wtu, v3[k], fmaf(wtl, v4[k], q));
        u = fmaf(Wih[wave * H + k], hx[k], u);
    }
    #pragma unroll
    for (int off = 32; off > 0; off >>= 1) {
        p += __shfl_down(p, off, 64);
        q += __shfl_down(q, off, 64);
        u += __shfl_down(u, off, 64);
    }
    if (lane == 0) {
        pqu[wave]         = p;
        pqu[H + wave]     = q;
        pqu[2 * H + wave] = u;
    }
}

// Kernel 2b: out[h] = sigmoid( Wsu[h,:]·p + Wsl[h,:]·q + u[h] )
__global__ __launch_bounds__(256) void strnn_out(
    const float* __restrict__ Wsu, const float* __restrict__ Wsl,
    const float* __restrict__ pqu, float* __restrict__ out)
{
    const int wave = (blockIdx.x * blockDim.x + threadIdx.x) >> 6;  // = h
    const int lane = threadIdx.x & 63;
    const float* p = pqu;
    const float* q = pqu + H;
    const float* u = pqu + 2 * H;

    float s = 0.f;
    #pragma unroll
    for (int i = 0; i < H; i += 64) {
        const int k = i + lane;
        s = fmaf(Wsu[wave * H + k], p[k], fmaf(Wsl[wave * H + k], q[k], s));
    }
    #pragma unroll
    for (int off = 32; off > 0; off >>= 1)
        s += __shfl_down(s, off, 64);
    if (lane == 0)
        out[wave] = 1.f / (1.f + expf(-(s + u[wave])));
}

extern "C" void kernel_launch(void* const* d_in, const int* in_sizes, int n_in,
                              void* d_out, int out_size, void* d_ws, size_t ws_size,
                              hipStream_t stream) {
    const float* td_u  = (const float*)d_in[0];
    const float* td_l  = (const float*)d_in[1];
    const float* ld_u  = (const float*)d_in[2];
    const float* ld_l  = (const float*)d_in[3];
    const int*   loc   = (const int*)d_in[4];
    const float* hx    = (const float*)d_in[5];
    const float* Wih   = (const float*)d_in[6];
    const float* Wtu   = (const float*)d_in[7];
    const float* Wtl   = (const float*)d_in[8];
    const float* Wsu   = (const float*)d_in[9];
    const float* Wsl   = (const float*)d_in[10];
    const float* table = (const float*)d_in[11];
    const int L = in_sizes[0];

    float* v   = (float*)d_ws;   // 4*H accumulators
    float* pqu = v + 4 * H;      // p, q, usr (3*H)

    // ws is re-poisoned to 0xAA before every launch — zero the accumulators.
    hipMemsetAsync(v, 0, 4 * H * sizeof(float), stream);

    strnn_gather<<<512, 256, 0, stream>>>(td_u, td_l, ld_u, ld_l, loc, table, v, L);
    strnn_mid<<<64, 256, 0, stream>>>(Wtu, Wtl, Wih, hx, v, pqu);
    strnn_out<<<64, 256, 0, stream>>>(Wsu, Wsl, pqu, (float*)d_out);
}